// Round 2
// baseline (369.133 us; speedup 1.0000x reference)
//
#include <hip/hip_runtime.h>

#define HID 20

// tanh via exp2 + rcp: tanh(v) = 1 - 2/(exp2(v*2*log2 e)+1). Saturates correctly.
static __device__ __forceinline__ float tanh_fast(float v) {
    const float e = __builtin_amdgcn_exp2f(v * 2.8853900817779268f);
    const float r = __builtin_amdgcn_rcpf(e + 1.0f);
    return fmaf(-2.0f, r, 1.0f);
}

// 64-lane shuffle reduce -> cross-wave LDS -> one f64 atomic per block
__device__ __forceinline__ void block_reduce_atomic(float local, double* dst) {
    #pragma unroll
    for (int off = 32; off > 0; off >>= 1) local += __shfl_down(local, off);
    __shared__ float parts[4];
    const int lane = threadIdx.x & 63, wid = threadIdx.x >> 6;
    if (lane == 0) parts[wid] = local;
    __syncthreads();
    if (threadIdx.x == 0)
        atomicAdd(dst, (double)(parts[0] + parts[1] + parts[2] + parts[3]));
}

// One hidden layer with 4-channel dual numbers (value, d/dt, d/dx, d2/dx2).
// W,b point to GLOBAL memory; all indices are compile-time after unroll ->
// uniform addresses -> scalarized s_load; FMA reads the weight from SGPR.
__device__ __forceinline__ void layer_dual(
    const float* __restrict__ W, const float* __restrict__ b,
    const float (&h)[HID], const float (&ha)[HID],
    const float (&hc)[HID], const float (&he)[HID],
    float (&nh)[HID], float (&nha)[HID], float (&nhc)[HID], float (&nhe)[HID])
{
    #pragma unroll
    for (int j0 = 0; j0 < HID; j0 += 4) {
        float av[4], aa[4], ac[4], ae[4];
        #pragma unroll
        for (int k = 0; k < 4; ++k) { av[k] = b[j0 + k]; aa[k] = 0.f; ac[k] = 0.f; ae[k] = 0.f; }
        #pragma unroll
        for (int i = 0; i < HID; ++i) {
            #pragma unroll
            for (int k = 0; k < 4; ++k) {
                const float wv = W[i * HID + j0 + k];
                av[k] = fmaf(wv, h[i],  av[k]);
                aa[k] = fmaf(wv, ha[i], aa[k]);
                ac[k] = fmaf(wv, hc[i], ac[k]);
                ae[k] = fmaf(wv, he[i], ae[k]);
            }
        }
        #pragma unroll
        for (int k = 0; k < 4; ++k) {
            const float th = tanh_fast(av[k]);
            const float s  = fmaf(-th, th, 1.0f);   // sech^2
            const float sc = s * ac[k];
            nh[j0 + k]  = th;
            nha[j0 + k] = s * aa[k];
            nhc[j0 + k] = sc;
            // y_xx = s*p_xx - 2*y*s*p_x^2 = fma(-2*th*sc, p_x, s*p_xx)
            nhe[j0 + k] = fmaf((-2.0f * th) * sc, ac[k], s * ae[k]);
        }
    }
}

// value-only hidden layer
__device__ __forceinline__ void layer_val(
    const float* __restrict__ W, const float* __restrict__ b,
    const float (&h)[HID], float (&nh)[HID])
{
    #pragma unroll
    for (int j0 = 0; j0 < HID; j0 += 4) {
        float acc[4];
        #pragma unroll
        for (int k = 0; k < 4; ++k) acc[k] = b[j0 + k];
        #pragma unroll
        for (int i = 0; i < HID; ++i) {
            #pragma unroll
            for (int k = 0; k < 4; ++k)
                acc[k] = fmaf(W[i * HID + j0 + k], h[i], acc[k]);
        }
        #pragma unroll
        for (int k = 0; k < 4; ++k) nh[j0 + k] = tanh_fast(acc[k]);
    }
}

__device__ __forceinline__ void coll_point(
    float tv, float xv,
    const float* __restrict__ W1, const float* __restrict__ b1,
    const float* __restrict__ W2, const float* __restrict__ b2,
    const float* __restrict__ W3, const float* __restrict__ b3,
    const float* __restrict__ W4, const float* __restrict__ b4,
    float nu, float& out)
{
    float h[HID], ha[HID], hc[HID], he[HID];
    #pragma unroll
    for (int j = 0; j < HID; ++j) {
        const float w0 = W1[j];
        const float w1 = W1[HID + j];
        const float p  = fmaf(tv, w0, fmaf(xv, w1, b1[j]));
        const float th = tanh_fast(p);
        const float s  = fmaf(-th, th, 1.0f);
        const float sc = s * w1;
        h[j]  = th;
        ha[j] = s * w0;
        hc[j] = sc;
        he[j] = (-2.0f * th) * sc * w1;
    }
    float g[HID], ga[HID], gc[HID], ge[HID];
    layer_dual(W2, b2, h, ha, hc, he, g, ga, gc, ge);
    layer_dual(W3, b3, g, ga, gc, ge, h, ha, hc, he);
    float u = b4[0], ut = 0.f, ux = 0.f, uxx = 0.f;
    #pragma unroll
    for (int i = 0; i < HID; ++i) {
        const float wv = W4[i];
        u   = fmaf(wv, h[i],  u);
        ut  = fmaf(wv, ha[i], ut);
        ux  = fmaf(wv, hc[i], ux);
        uxx = fmaf(wv, he[i], uxx);
    }
    const float f = fmaf(u, ux, ut) - nu * uxx;
    out = f * f;
}

__device__ __forceinline__ void data_point(
    float tv, float xv, float ut_true,
    const float* __restrict__ W1, const float* __restrict__ b1,
    const float* __restrict__ W2, const float* __restrict__ b2,
    const float* __restrict__ W3, const float* __restrict__ b3,
    const float* __restrict__ W4, const float* __restrict__ b4,
    float& out)
{
    float h[HID], g[HID];
    #pragma unroll
    for (int j = 0; j < HID; ++j)
        h[j] = tanh_fast(fmaf(tv, W1[j], fmaf(xv, W1[HID + j], b1[j])));
    layer_val(W2, b2, h, g);
    layer_val(W3, b3, g, h);
    float u = b4[0];
    #pragma unroll
    for (int i = 0; i < HID; ++i) u = fmaf(W4[i], h[i], u);
    const float d = u - ut_true;
    out = d * d;
}

// One fused dispatch: blocks [0,CB) collocation, [CB,CB+IB) initial, rest boundary.
__global__ __launch_bounds__(256) void k_all(
    const float* __restrict__ t_c, const float* __restrict__ x_c,
    const float* __restrict__ t_i, const float* __restrict__ x_i, const float* __restrict__ u_i,
    const float* __restrict__ t_b, const float* __restrict__ x_b, const float* __restrict__ u_b,
    const float* __restrict__ W1, const float* __restrict__ b1,
    const float* __restrict__ W2, const float* __restrict__ b2,
    const float* __restrict__ W3, const float* __restrict__ b3,
    const float* __restrict__ W4, const float* __restrict__ b4,
    double* __restrict__ sums,
    int N, int NI, int NB, int CB, int IB, float nu)
{
    const int b = blockIdx.x;
    float local = 0.0f;
    if (b < CB) {
        const int idx = b * 256 + threadIdx.x;
        if (idx < N)
            coll_point(t_c[idx], x_c[idx], W1, b1, W2, b2, W3, b3, W4, b4, nu, local);
        block_reduce_atomic(local, sums + 0);
    } else if (b < CB + IB) {
        const int idx = (b - CB) * 256 + threadIdx.x;
        if (idx < NI)
            data_point(t_i[idx], x_i[idx], u_i[idx], W1, b1, W2, b2, W3, b3, W4, b4, local);
        block_reduce_atomic(local, sums + 1);
    } else {
        const int idx = (b - CB - IB) * 256 + threadIdx.x;
        if (idx < NB)
            data_point(t_b[idx], x_b[idx], u_b[idx], W1, b1, W2, b2, W3, b3, W4, b4, local);
        block_reduce_atomic(local, sums + 2);
    }
}

__global__ void k_zero(double* sums) {
    if (threadIdx.x < 3) sums[threadIdx.x] = 0.0;
}

__global__ void k_fin(const double* __restrict__ sums, float* __restrict__ out,
                      int N, int NI, int NB) {
    out[0] = (float)(sums[0] / (double)N + sums[1] / (double)NI + sums[2] / (double)NB);
}

extern "C" void kernel_launch(void* const* d_in, const int* in_sizes, int n_in,
                              void* d_out, int out_size, void* d_ws, size_t ws_size,
                              hipStream_t stream) {
    const float* t_c = (const float*)d_in[0];
    const float* x_c = (const float*)d_in[1];
    const float* t_i = (const float*)d_in[2];
    const float* x_i = (const float*)d_in[3];
    const float* u_i = (const float*)d_in[4];
    const float* t_b = (const float*)d_in[5];
    const float* x_b = (const float*)d_in[6];
    const float* u_b = (const float*)d_in[7];
    const float* W1  = (const float*)d_in[8];
    const float* b1  = (const float*)d_in[9];
    const float* W2  = (const float*)d_in[10];
    const float* b2  = (const float*)d_in[11];
    const float* W3  = (const float*)d_in[12];
    const float* b3  = (const float*)d_in[13];
    const float* W4  = (const float*)d_in[14];
    const float* b4  = (const float*)d_in[15];

    const int N  = in_sizes[0];
    const int NI = in_sizes[2];
    const int NB = in_sizes[5];
    const float nu = 0.0031830988618379067f;  // 0.01/pi

    const int CB = (N + 255) / 256;
    const int IB = (NI + 255) / 256;
    const int BB = (NB + 255) / 256;

    double* sums = (double*)d_ws;

    k_zero<<<1, 64, 0, stream>>>(sums);
    k_all<<<CB + IB + BB, 256, 0, stream>>>(t_c, x_c, t_i, x_i, u_i, t_b, x_b, u_b,
                                            W1, b1, W2, b2, W3, b3, W4, b4,
                                            sums, N, NI, NB, CB, IB, nu);
    k_fin<<<1, 1, 0, stream>>>(sums, (float*)d_out, N, NI, NB);
}

// Round 3
// 166.345 us; speedup vs baseline: 2.2191x; 2.2191x over previous
//
#include <hip/hip_runtime.h>

#define HID 20

typedef _Float16 half8 __attribute__((ext_vector_type(8)));
typedef float f32x16 __attribute__((ext_vector_type(16)));

// tanh via exp2 + rcp: tanh(v) = 1 - 2/(exp2(v*2*log2e)+1). Saturates correctly at +-inf.
static __device__ __forceinline__ float tanh_fast(float v) {
    const float e = __builtin_amdgcn_exp2f(v * 2.8853900817779268f);
    const float r = __builtin_amdgcn_rcpf(e + 1.0f);
    return fmaf(-2.0f, r, 1.0f);
}

// v_permlane32_swap_b32: x.high(lanes32-63) <-> y.low(lanes0-31).
// After: x = {x.low, y.low-moved-up}, y = {x.high-moved-down, y.high}.
static __device__ __forceinline__ void swap_halves(float& x, float& y) {
    asm volatile("v_permlane32_swap_b32 %0, %1" : "+v"(x), "+v"(y));
}

// 64-lane shuffle reduce -> cross-wave LDS -> one f64 atomic per block
__device__ __forceinline__ void block_reduce_atomic(float local, double* dst) {
    #pragma unroll
    for (int off = 32; off > 0; off >>= 1) local += __shfl_down(local, off);
    __shared__ float parts[4];
    const int lane = threadIdx.x & 63, wid = threadIdx.x >> 6;
    if (lane == 0) parts[wid] = local;
    __syncthreads();
    if (threadIdx.x == 0)
        atomicAdd(dst, (double)(parts[0] + parts[1] + parts[2] + parts[3]));
}

// ---------------------------------------------------------------------------
// Collocation kernel: 4-channel dual numbers (u, u_t, u_x, u_xx) through the
// MLP with the two 20x20 layers done as fp16 MFMA (swapped orientation:
// D = Wt * Ht so the point index stays in the column = lane&31 for both the
// B operand and the D result -> no transpose between layers).
//   A (Wt): row j = lane&31 (neuron out), k i = 16c + 8h + e (neuron in);
//           k row 20 carries the bias, rows >20 are zero.
//   B (Ht): col p = lane&31 (point), k = 16c + 8h + e; slot k==20 is 1.0 for
//           the value channel / 0.0 for the dual channels (bias has no dual).
//   D:      col p = lane&31, neuron row = (r&3) + 8(r>>2) + 4h   [verified map]
// D -> next-B redistribution: one v_permlane32_swap_b32 per (c, e<4) pair
// yields both slot e and slot e+4.
// ---------------------------------------------------------------------------
__global__ __launch_bounds__(256) void k_coll_mfma(
    const float* __restrict__ tc, const float* __restrict__ xc,
    const float* __restrict__ W1, const float* __restrict__ b1,
    const float* __restrict__ W2, const float* __restrict__ b2,
    const float* __restrict__ W3, const float* __restrict__ b3,
    const float* __restrict__ W4, const float* __restrict__ b4,
    double* __restrict__ sum_out, int N, float nu)
{
    __shared__ float sW0[32], sW1v[32], sB1[32];
    const int tid = threadIdx.x;
    if (tid < 32) {
        sW0[tid]  = (tid < HID) ? W1[tid]       : 0.0f;
        sW1v[tid] = (tid < HID) ? W1[HID + tid] : 0.0f;
        sB1[tid]  = (tid < HID) ? b1[tid]       : 0.0f;
    }
    __syncthreads();

    const int lane = tid & 63;
    const int h    = lane >> 5;    // lane half
    const int colp = lane & 31;    // point-within-tile; also A row (neuron j)

    // --- per-wave setup: A fragments for W2,W3 (+bias row), W4 in D layout ---
    half8 A2[2], A3[2];
    #pragma unroll
    for (int c = 0; c < 2; ++c) {
        #pragma unroll
        for (int e = 0; e < 8; ++e) {
            const int i = 16 * c + 8 * h + e;   // k index = input neuron
            float v2 = 0.0f, v3 = 0.0f;
            if (colp < HID) {
                if (i < HID)       { v2 = W2[i * HID + colp]; v3 = W3[i * HID + colp]; }
                else if (i == HID) { v2 = b2[colp];           v3 = b3[colp]; }
            }
            A2[c][e] = (_Float16)v2;
            A3[c][e] = (_Float16)v3;
        }
    }
    float w4v[16];
    #pragma unroll
    for (int r = 0; r < 16; ++r) {
        const int row = (r & 3) + 8 * (r >> 2) + 4 * h;
        w4v[r] = (row < HID) ? W4[row] : 0.0f;
    }
    const float b4v = b4[0];

    const int wave  = (int)((blockIdx.x * blockDim.x + tid) >> 6);
    const int nwave = (int)((gridDim.x * blockDim.x) >> 6);
    const int ntile = (N + 31) >> 5;

    float local = 0.0f;
    for (int tile = wave; tile < ntile; tile += nwave) {
        const int  idx   = (tile << 5) + colp;
        const bool valid = idx < N;
        const int  ia    = valid ? idx : 0;
        const float tv = tc[ia], xv = xc[ia];

        // --- layer 1 on VALU, produced directly in B-fragment layout ---
        half8 Bv[2], Ba[2], Bc[2], Be[2];
        #pragma unroll
        for (int c = 0; c < 2; ++c) {
            #pragma unroll
            for (int e = 0; e < 8; ++e) {
                const int n = 16 * c + 8 * h + e;      // LDS addr (runtime ok)
                const float w0 = sW0[n], w1 = sW1v[n], bb = sB1[n];
                const float p  = fmaf(tv, w0, fmaf(xv, w1, bb));
                const float th = tanh_fast(p);
                const float s  = fmaf(-th, th, 1.0f);
                const float q  = s * w1;
                float vv = th, va = s * w0, vc = q, ve = -((th + th) * q) * w1;
                if (c == 1 && e == 4) { vv = 1.0f; va = 0.0f; vc = 0.0f; ve = 0.0f; } // bias slot k=20
                Bv[c][e] = (_Float16)vv; Ba[c][e] = (_Float16)va;
                Bc[c][e] = (_Float16)vc; Be[c][e] = (_Float16)ve;
            }
        }

        // --- layer 2 MFMA ---
        f32x16 Dv, Da, Dc, De;
        #pragma unroll
        for (int r = 0; r < 16; ++r) { Dv[r] = 0.f; Da[r] = 0.f; Dc[r] = 0.f; De[r] = 0.f; }
        #pragma unroll
        for (int c = 0; c < 2; ++c) {
            Dv = __builtin_amdgcn_mfma_f32_32x32x16_f16(A2[c], Bv[c], Dv, 0, 0, 0);
            Da = __builtin_amdgcn_mfma_f32_32x32x16_f16(A2[c], Ba[c], Da, 0, 0, 0);
            Dc = __builtin_amdgcn_mfma_f32_32x32x16_f16(A2[c], Bc[c], Dc, 0, 0, 0);
            De = __builtin_amdgcn_mfma_f32_32x32x16_f16(A2[c], Be[c], De, 0, 0, 0);
        }
        // --- tanh + dual-chain epilogue (in place; pad rows are exact 0) ---
        #pragma unroll
        for (int r = 0; r < 16; ++r) {
            const float zv = Dv[r], za = Da[r], zc = Dc[r], ze = De[r];
            const float th = tanh_fast(zv);
            const float s  = fmaf(-th, th, 1.0f);
            const float q  = s * zc;
            Dv[r] = th;
            Da[r] = s * za;
            Dc[r] = q;
            De[r] = fmaf(s, ze, -((th + th) * q) * zc);
        }
        // --- redistribute D -> B fragments for layer 3 ---
        #pragma unroll
        for (int c = 0; c < 2; ++c) {
            #pragma unroll
            for (int e = 0; e < 4; ++e) {
                float x0, y0;
                x0 = Dv[8*c + e]; y0 = Dv[8*c + 4 + e]; swap_halves(x0, y0);
                Bv[c][e] = (_Float16)x0; Bv[c][e + 4] = (_Float16)y0;
                x0 = Da[8*c + e]; y0 = Da[8*c + 4 + e]; swap_halves(x0, y0);
                Ba[c][e] = (_Float16)x0; Ba[c][e + 4] = (_Float16)y0;
                x0 = Dc[8*c + e]; y0 = Dc[8*c + 4 + e]; swap_halves(x0, y0);
                Bc[c][e] = (_Float16)x0; Bc[c][e + 4] = (_Float16)y0;
                x0 = De[8*c + e]; y0 = De[8*c + 4 + e]; swap_halves(x0, y0);
                Be[c][e] = (_Float16)x0; Be[c][e + 4] = (_Float16)y0;
            }
        }
        // bias slot k=20 for layer 3
        Bv[1][4] = (_Float16)1.0f; Ba[1][4] = (_Float16)0.0f;
        Bc[1][4] = (_Float16)0.0f; Be[1][4] = (_Float16)0.0f;

        // --- layer 3 MFMA ---
        #pragma unroll
        for (int r = 0; r < 16; ++r) { Dv[r] = 0.f; Da[r] = 0.f; Dc[r] = 0.f; De[r] = 0.f; }
        #pragma unroll
        for (int c = 0; c < 2; ++c) {
            Dv = __builtin_amdgcn_mfma_f32_32x32x16_f16(A3[c], Bv[c], Dv, 0, 0, 0);
            Da = __builtin_amdgcn_mfma_f32_32x32x16_f16(A3[c], Ba[c], Da, 0, 0, 0);
            Dc = __builtin_amdgcn_mfma_f32_32x32x16_f16(A3[c], Bc[c], Dc, 0, 0, 0);
            De = __builtin_amdgcn_mfma_f32_32x32x16_f16(A3[c], Be[c], De, 0, 0, 0);
        }
        #pragma unroll
        for (int r = 0; r < 16; ++r) {
            const float zv = Dv[r], za = Da[r], zc = Dc[r], ze = De[r];
            const float th = tanh_fast(zv);
            const float s  = fmaf(-th, th, 1.0f);
            const float q  = s * zc;
            Dv[r] = th;
            Da[r] = s * za;
            Dc[r] = q;
            De[r] = fmaf(s, ze, -((th + th) * q) * zc);
        }

        // --- output layer: dot with W4 (rows >=20 are zero in w4v) ---
        float u = 0.f, ut = 0.f, ux = 0.f, uxx = 0.f;
        #pragma unroll
        for (int r = 0; r < 16; ++r) {
            u   = fmaf(w4v[r], Dv[r], u);
            ut  = fmaf(w4v[r], Da[r], ut);
            ux  = fmaf(w4v[r], Dc[r], ux);
            uxx = fmaf(w4v[r], De[r], uxx);
        }
        u   += __shfl_xor(u, 32);
        ut  += __shfl_xor(ut, 32);
        ux  += __shfl_xor(ux, 32);
        uxx += __shfl_xor(uxx, 32);
        u   += b4v;

        float f = fmaf(u, ux, ut);
        f = fmaf(-nu, uxx, f);
        if (h == 0 && valid) local += f * f;
    }
    block_reduce_atomic(local, sum_out);
}

// ---------------------------------------------------------------------------
// Initial/boundary residual: value-only fp32 VALU forward (round-1 proven).
// ---------------------------------------------------------------------------
struct WeightsLDS {
    float W1[2 * HID];
    float b1[HID];
    float W2[HID * HID];
    float b2[HID];
    float W3[HID * HID];
    float b3[HID];
    float W4[HID];
    float b4;
};

__device__ __forceinline__ void load_weights(WeightsLDS& w,
    const float* __restrict__ W1, const float* __restrict__ b1,
    const float* __restrict__ W2, const float* __restrict__ b2,
    const float* __restrict__ W3, const float* __restrict__ b3,
    const float* __restrict__ W4, const float* __restrict__ b4)
{
    const int tid = threadIdx.x;
    for (int k = tid; k < 2 * HID; k += 256)   w.W1[k] = W1[k];
    for (int k = tid; k < HID; k += 256)       w.b1[k] = b1[k];
    for (int k = tid; k < HID * HID; k += 256) w.W2[k] = W2[k];
    for (int k = tid; k < HID; k += 256)       w.b2[k] = b2[k];
    for (int k = tid; k < HID * HID; k += 256) w.W3[k] = W3[k];
    for (int k = tid; k < HID; k += 256)       w.b3[k] = b3[k];
    for (int k = tid; k < HID; k += 256)       w.W4[k] = W4[k];
    if (tid == 0) w.b4 = b4[0];
    __syncthreads();
}

__global__ __launch_bounds__(256) void k_data(
    const float* __restrict__ tt, const float* __restrict__ xx,
    const float* __restrict__ utrue,
    const float* __restrict__ W1, const float* __restrict__ b1,
    const float* __restrict__ W2, const float* __restrict__ b2,
    const float* __restrict__ W3, const float* __restrict__ b3,
    const float* __restrict__ W4, const float* __restrict__ b4,
    double* __restrict__ sum_out, int n)
{
    __shared__ WeightsLDS w;
    load_weights(w, W1, b1, W2, b2, W3, b3, W4, b4);

    const int idx = blockIdx.x * 256 + threadIdx.x;
    float local = 0.0f;
    if (idx < n) {
        const float tv = tt[idx], xv = xx[idx];
        float h[HID], g[HID];
        #pragma unroll
        for (int j = 0; j < HID; ++j)
            h[j] = tanh_fast(fmaf(tv, w.W1[j], fmaf(xv, w.W1[HID + j], w.b1[j])));
        #pragma unroll
        for (int j0 = 0; j0 < HID; j0 += 4) {
            float acc[4];
            #pragma unroll
            for (int k = 0; k < 4; ++k) acc[k] = w.b2[j0 + k];
            #pragma unroll
            for (int i = 0; i < HID; ++i) {
                #pragma unroll
                for (int k = 0; k < 4; ++k)
                    acc[k] = fmaf(w.W2[i * HID + j0 + k], h[i], acc[k]);
            }
            #pragma unroll
            for (int k = 0; k < 4; ++k) g[j0 + k] = tanh_fast(acc[k]);
        }
        #pragma unroll
        for (int j0 = 0; j0 < HID; j0 += 4) {
            float acc[4];
            #pragma unroll
            for (int k = 0; k < 4; ++k) acc[k] = w.b3[j0 + k];
            #pragma unroll
            for (int i = 0; i < HID; ++i) {
                #pragma unroll
                for (int k = 0; k < 4; ++k)
                    acc[k] = fmaf(w.W3[i * HID + j0 + k], g[i], acc[k]);
            }
            #pragma unroll
            for (int k = 0; k < 4; ++k) h[j0 + k] = tanh_fast(acc[k]);
        }
        float u = w.b4;
        #pragma unroll
        for (int i = 0; i < HID; ++i) u = fmaf(w.W4[i], h[i], u);
        const float d = u - utrue[idx];
        local = d * d;
    }
    block_reduce_atomic(local, sum_out);
}

__global__ void k_zero(double* sums) {
    if (threadIdx.x < 3) sums[threadIdx.x] = 0.0;
}

__global__ void k_fin(const double* __restrict__ sums, float* __restrict__ out,
                      int N, int NI, int NB) {
    out[0] = (float)(sums[0] / (double)N + sums[1] / (double)NI + sums[2] / (double)NB);
}

extern "C" void kernel_launch(void* const* d_in, const int* in_sizes, int n_in,
                              void* d_out, int out_size, void* d_ws, size_t ws_size,
                              hipStream_t stream) {
    const float* t_c = (const float*)d_in[0];
    const float* x_c = (const float*)d_in[1];
    const float* t_i = (const float*)d_in[2];
    const float* x_i = (const float*)d_in[3];
    const float* u_i = (const float*)d_in[4];
    const float* t_b = (const float*)d_in[5];
    const float* x_b = (const float*)d_in[6];
    const float* u_b = (const float*)d_in[7];
    const float* W1  = (const float*)d_in[8];
    const float* b1  = (const float*)d_in[9];
    const float* W2  = (const float*)d_in[10];
    const float* b2  = (const float*)d_in[11];
    const float* W3  = (const float*)d_in[12];
    const float* b3  = (const float*)d_in[13];
    const float* W4  = (const float*)d_in[14];
    const float* b4  = (const float*)d_in[15];

    const int N  = in_sizes[0];
    const int NI = in_sizes[2];
    const int NB = in_sizes[5];
    const float nu = 0.0031830988618379067f;  // 0.01/pi

    double* sums = (double*)d_ws;

    k_zero<<<1, 64, 0, stream>>>(sums);
    k_coll_mfma<<<2048, 256, 0, stream>>>(t_c, x_c, W1, b1, W2, b2, W3, b3, W4, b4,
                                          sums + 0, N, nu);
    k_data<<<(NI + 255) / 256, 256, 0, stream>>>(t_i, x_i, u_i, W1, b1, W2, b2, W3, b3, W4, b4,
                                                 sums + 1, NI);
    k_data<<<(NB + 255) / 256, 256, 0, stream>>>(t_b, x_b, u_b, W1, b1, W2, b2, W3, b3, W4, b4,
                                                 sums + 2, NB);
    k_fin<<<1, 1, 0, stream>>>(sums, (float*)d_out, N, NI, NB);
}

// Round 5
// 112.553 us; speedup vs baseline: 3.2796x; 1.4779x over previous
//
#include <hip/hip_runtime.h>

#define HID 20

typedef _Float16 half8  __attribute__((ext_vector_type(8)));
typedef _Float16 half2t __attribute__((ext_vector_type(2)));
typedef float    f32x16 __attribute__((ext_vector_type(16)));

union H8 { half8 v8; half2t d[4]; };   // build fp16 fragment dword-by-dword

// tanh via exp2 + rcp: tanh(v) = 1 - 2/(exp2(v*2*log2e)+1). Saturates at +-inf.
static __device__ __forceinline__ float tanh_fast(float v) {
    const float e = __builtin_amdgcn_exp2f(v * 2.8853900817779268f);
    const float r = __builtin_amdgcn_rcpf(e + 1.0f);
    return fmaf(-2.0f, r, 1.0f);
}

// v_cvt_pkrtz_f16_f32: pack two f32 into one dword of two fp16 (RTZ).
// Builtin returns __fp16-element vector; bit-cast to _Float16-element.
static __device__ __forceinline__ half2t pk(float a, float b) {
    auto r = __builtin_amdgcn_cvt_pkrtz(a, b);
    half2t out;
    __builtin_memcpy(&out, &r, sizeof(out));
    return out;
}

// v_permlane32_swap_b32: new_x[l>=32] = old_y[l-32]; new_y[l<32] = old_x[l+32].
static __device__ __forceinline__ void swap_halves(float& x, float& y) {
    asm volatile("v_permlane32_swap_b32 %0, %1" : "+v"(x), "+v"(y));
}

// 64-lane shuffle reduce -> cross-wave LDS -> one f64 atomic per block.
// Entry barrier makes back-to-back calls safe (parts[] reuse).
__device__ __forceinline__ void block_reduce_atomic(float local, double* dst) {
    #pragma unroll
    for (int off = 32; off > 0; off >>= 1) local += __shfl_down(local, off);
    __shared__ float parts[4];
    __syncthreads();
    const int lane = threadIdx.x & 63, wid = threadIdx.x >> 6;
    if (lane == 0) parts[wid] = local;
    __syncthreads();
    if (threadIdx.x == 0)
        atomicAdd(dst, (double)(parts[0] + parts[1] + parts[2] + parts[3]));
}

// ---------------------------------------------------------------------------
// Fused kernel. Blocks [0, CBLK): collocation (4 dual channels).
//               Blocks [CBLK, CBLK+DBLK): initial+boundary (value only).
// Swapped MFMA orientation: D = Wt * Ht, point = column = lane&31 for B and D.
//   A (Wt): M-row = lane&31 (out neuron), k = 16c + 8h + e (in neuron);
//           k==20 carries the bias; rows/cols >= 20 are zero.
//   D:      col = lane&31 (point), row = (r&3) + 8(r>>2) + 4h.
// Rows >= 20 of D are exactly 0 => epilogue only r<12; pack c=1 needs no swap.
// ---------------------------------------------------------------------------
__global__ __launch_bounds__(256) void k_fused(
    const float* __restrict__ t_c, const float* __restrict__ x_c,
    const float* __restrict__ t_i, const float* __restrict__ x_i, const float* __restrict__ u_i,
    const float* __restrict__ t_b, const float* __restrict__ x_b, const float* __restrict__ u_b,
    const float* __restrict__ W1, const float* __restrict__ b1,
    const float* __restrict__ W2, const float* __restrict__ b2,
    const float* __restrict__ W3, const float* __restrict__ b3,
    const float* __restrict__ W4, const float* __restrict__ b4,
    double* __restrict__ sums,
    int N, int NI, int NB, int CBLK, int DBLK, float nu)
{
    __shared__ float4 sL[32];          // {W1_t, W1_x, b1, 0} per layer-1 slot
    const int tid = threadIdx.x;
    if (tid < 32) {
        const bool r = tid < HID;
        sL[tid] = make_float4(r ? W1[tid] : 0.f, r ? W1[HID + tid] : 0.f,
                              r ? b1[tid] : 0.f, 0.f);
    }
    __syncthreads();

    const int lane = tid & 63;
    const int h    = lane >> 5;
    const int colp = lane & 31;

    // A fragments for W2,W3 (+bias row k=20); W4 in D layout (live rows only)
    half8 A2[2], A3[2];
    #pragma unroll
    for (int c = 0; c < 2; ++c) {
        #pragma unroll
        for (int e = 0; e < 8; ++e) {
            const int i = 16 * c + 8 * h + e;
            float v2 = 0.f, v3 = 0.f;
            if (colp < HID) {
                if (i < HID)       { v2 = W2[i * HID + colp]; v3 = W3[i * HID + colp]; }
                else if (i == HID) { v2 = b2[colp];           v3 = b3[colp]; }
            }
            A2[c][e] = (_Float16)v2;
            A3[c][e] = (_Float16)v3;
        }
    }
    float w4v[12];
    #pragma unroll
    for (int r = 0; r < 12; ++r) {
        const int row = (r & 3) + 8 * (r >> 2) + 4 * h;
        w4v[r] = (row < HID) ? W4[row] : 0.0f;
    }
    const float b4v = b4[0];
    const half2t Z2   = {(_Float16)0.0f, (_Float16)0.0f};
    const half2t ONE0 = {(_Float16)1.0f, (_Float16)0.0f};

    if ((int)blockIdx.x < CBLK) {
        // ================= collocation: 4 dual channels =================
        const int wave  = (int)blockIdx.x * 4 + (tid >> 6);
        const int nwave = CBLK * 4;
        const int ntile = (N + 31) >> 5;

        float local = 0.0f;
        for (int tile = wave; tile < ntile; tile += nwave) {
            const int  idx   = (tile << 5) + colp;
            const bool valid = idx < N;
            const int  ia    = valid ? idx : 0;
            const float tv = t_c[ia], xv = x_c[ia];

            // layer-1 slot: p = t*w.x + x*w.y + w.z ; duals from (w.x, w.y)
            auto l1 = [&](int e, int c, float& vv, float& va, float& vc, float& ve) {
                const int n = 16 * c + 8 * h + e;
                const float4 w = sL[n];
                const float p  = fmaf(tv, w.x, fmaf(xv, w.y, w.z));
                const float th = tanh_fast(p);
                const float s  = fmaf(-th, th, 1.0f);
                const float q  = s * w.y;
                vv = th; va = s * w.x; vc = q; ve = -((th + th) * q) * w.y;
            };

            H8 Bv[2], Ba[2], Bc[2], Be[2];
            #pragma unroll
            for (int d2 = 0; d2 < 4; ++d2) {       // c=0, slot pairs
                float v0,a0,c0,e0, v1,a1,c1,e1;
                l1(2*d2,     0, v0,a0,c0,e0);
                l1(2*d2 + 1, 0, v1,a1,c1,e1);
                Bv[0].d[d2] = pk(v0,v1); Ba[0].d[d2] = pk(a0,a1);
                Bc[0].d[d2] = pk(c0,c1); Be[0].d[d2] = pk(e0,e1);
            }
            #pragma unroll
            for (int d2 = 0; d2 < 2; ++d2) {       // c=1, slots 16..19
                float v0,a0,c0,e0, v1,a1,c1,e1;
                l1(2*d2,     1, v0,a0,c0,e0);
                l1(2*d2 + 1, 1, v1,a1,c1,e1);
                Bv[1].d[d2] = pk(v0,v1); Ba[1].d[d2] = pk(a0,a1);
                Bc[1].d[d2] = pk(c0,c1); Be[1].d[d2] = pk(e0,e1);
            }
            Bv[1].d[2] = ONE0; Ba[1].d[2] = Z2; Bc[1].d[2] = Z2; Be[1].d[2] = Z2; // bias k=20
            Bv[1].d[3] = Z2;   Ba[1].d[3] = Z2; Bc[1].d[3] = Z2; Be[1].d[3] = Z2;

            f32x16 Dv, Da, Dc, De;
            #pragma unroll
            for (int r = 0; r < 16; ++r) { Dv[r]=0.f; Da[r]=0.f; Dc[r]=0.f; De[r]=0.f; }
            #pragma unroll
            for (int c = 0; c < 2; ++c) {
                Dv = __builtin_amdgcn_mfma_f32_32x32x16_f16(A2[c], Bv[c].v8, Dv, 0,0,0);
                Da = __builtin_amdgcn_mfma_f32_32x32x16_f16(A2[c], Ba[c].v8, Da, 0,0,0);
                Dc = __builtin_amdgcn_mfma_f32_32x32x16_f16(A2[c], Bc[c].v8, Dc, 0,0,0);
                De = __builtin_amdgcn_mfma_f32_32x32x16_f16(A2[c], Be[c].v8, De, 0,0,0);
            }
            #pragma unroll
            for (int r = 0; r < 12; ++r) {          // rows >=24 are dead
                const float zv = Dv[r], za = Da[r], zc = Dc[r], ze = De[r];
                const float th = tanh_fast(zv);
                const float s  = fmaf(-th, th, 1.0f);
                const float q  = s * zc;
                Dv[r] = th; Da[r] = s * za; Dc[r] = q;
                De[r] = fmaf(s, ze, -((th + th) * q) * zc);
            }
            // pack D -> B: c=0 via swaps; c=1 straight (h=1 side is natural 0)
            #pragma unroll
            for (int d2 = 0; d2 < 2; ++d2) {
                float x0,y0,x1,y1;
                x0=Dv[2*d2]; y0=Dv[4+2*d2]; swap_halves(x0,y0);
                x1=Dv[2*d2+1]; y1=Dv[5+2*d2]; swap_halves(x1,y1);
                Bv[0].d[d2] = pk(x0,x1); Bv[0].d[2+d2] = pk(y0,y1);
                x0=Da[2*d2]; y0=Da[4+2*d2]; swap_halves(x0,y0);
                x1=Da[2*d2+1]; y1=Da[5+2*d2]; swap_halves(x1,y1);
                Ba[0].d[d2] = pk(x0,x1); Ba[0].d[2+d2] = pk(y0,y1);
                x0=Dc[2*d2]; y0=Dc[4+2*d2]; swap_halves(x0,y0);
                x1=Dc[2*d2+1]; y1=Dc[5+2*d2]; swap_halves(x1,y1);
                Bc[0].d[d2] = pk(x0,x1); Bc[0].d[2+d2] = pk(y0,y1);
                x0=De[2*d2]; y0=De[4+2*d2]; swap_halves(x0,y0);
                x1=De[2*d2+1]; y1=De[5+2*d2]; swap_halves(x1,y1);
                Be[0].d[d2] = pk(x0,x1); Be[0].d[2+d2] = pk(y0,y1);
            }
            Bv[1].d[0] = pk(Dv[8],Dv[9]); Bv[1].d[1] = pk(Dv[10],Dv[11]);
            Ba[1].d[0] = pk(Da[8],Da[9]); Ba[1].d[1] = pk(Da[10],Da[11]);
            Bc[1].d[0] = pk(Dc[8],Dc[9]); Bc[1].d[1] = pk(Dc[10],Dc[11]);
            Be[1].d[0] = pk(De[8],De[9]); Be[1].d[1] = pk(De[10],De[11]);
            Bv[1].d[2] = ONE0; Ba[1].d[2] = Z2; Bc[1].d[2] = Z2; Be[1].d[2] = Z2;
            Bv[1].d[3] = Z2;   Ba[1].d[3] = Z2; Bc[1].d[3] = Z2; Be[1].d[3] = Z2;

            #pragma unroll
            for (int r = 0; r < 16; ++r) { Dv[r]=0.f; Da[r]=0.f; Dc[r]=0.f; De[r]=0.f; }
            #pragma unroll
            for (int c = 0; c < 2; ++c) {
                Dv = __builtin_amdgcn_mfma_f32_32x32x16_f16(A3[c], Bv[c].v8, Dv, 0,0,0);
                Da = __builtin_amdgcn_mfma_f32_32x32x16_f16(A3[c], Ba[c].v8, Da, 0,0,0);
                Dc = __builtin_amdgcn_mfma_f32_32x32x16_f16(A3[c], Bc[c].v8, Dc, 0,0,0);
                De = __builtin_amdgcn_mfma_f32_32x32x16_f16(A3[c], Be[c].v8, De, 0,0,0);
            }
            #pragma unroll
            for (int r = 0; r < 12; ++r) {
                const float zv = Dv[r], za = Da[r], zc = Dc[r], ze = De[r];
                const float th = tanh_fast(zv);
                const float s  = fmaf(-th, th, 1.0f);
                const float q  = s * zc;
                Dv[r] = th; Da[r] = s * za; Dc[r] = q;
                De[r] = fmaf(s, ze, -((th + th) * q) * zc);
            }

            float u = 0.f, ut = 0.f, ux = 0.f, uxx = 0.f;
            #pragma unroll
            for (int r = 0; r < 12; ++r) {
                u   = fmaf(w4v[r], Dv[r], u);
                ut  = fmaf(w4v[r], Da[r], ut);
                ux  = fmaf(w4v[r], Dc[r], ux);
                uxx = fmaf(w4v[r], De[r], uxx);
            }
            u   += __shfl_xor(u, 32);
            ut  += __shfl_xor(ut, 32);
            ux  += __shfl_xor(ux, 32);
            uxx += __shfl_xor(uxx, 32);
            u   += b4v;

            float f = fmaf(u, ux, ut);
            f = fmaf(-nu, uxx, f);
            if (h == 0 && valid) local += f * f;
        }
        block_reduce_atomic(local, sums + 0);
    } else {
        // ============== initial + boundary: value channel only ==============
        const int dwave = ((int)blockIdx.x - CBLK) * 4 + (tid >> 6);
        const int dnw   = DBLK * 4;
        const int nti   = (NI + 31) >> 5;
        const int ntb   = (NB + 31) >> 5;

        float li = 0.0f, lbd = 0.0f;
        for (int t2 = dwave; t2 < nti + ntb; t2 += dnw) {
            const bool isB = t2 >= nti;               // wave-uniform
            const float* tp = isB ? t_b : t_i;
            const float* xp = isB ? x_b : x_i;
            const float* up = isB ? u_b : u_i;
            const int    n_ = isB ? NB  : NI;
            const int  idx  = (((isB ? t2 - nti : t2) << 5)) + colp;
            const bool valid = idx < n_;
            const int  ia    = valid ? idx : 0;
            const float tv = tp[ia], xv = xp[ia], uT = up[ia];

            auto l1v = [&](int e, int c) -> float {
                const int n = 16 * c + 8 * h + e;
                const float4 w = sL[n];
                return tanh_fast(fmaf(tv, w.x, fmaf(xv, w.y, w.z)));
            };

            H8 Bv[2];
            #pragma unroll
            for (int d2 = 0; d2 < 4; ++d2)
                Bv[0].d[d2] = pk(l1v(2*d2, 0), l1v(2*d2+1, 0));
            #pragma unroll
            for (int d2 = 0; d2 < 2; ++d2)
                Bv[1].d[d2] = pk(l1v(2*d2, 1), l1v(2*d2+1, 1));
            Bv[1].d[2] = ONE0; Bv[1].d[3] = Z2;

            f32x16 Dv;
            #pragma unroll
            for (int r = 0; r < 16; ++r) Dv[r] = 0.f;
            #pragma unroll
            for (int c = 0; c < 2; ++c)
                Dv = __builtin_amdgcn_mfma_f32_32x32x16_f16(A2[c], Bv[c].v8, Dv, 0,0,0);
            #pragma unroll
            for (int r = 0; r < 12; ++r) Dv[r] = tanh_fast(Dv[r]);

            #pragma unroll
            for (int d2 = 0; d2 < 2; ++d2) {
                float x0,y0,x1,y1;
                x0=Dv[2*d2]; y0=Dv[4+2*d2]; swap_halves(x0,y0);
                x1=Dv[2*d2+1]; y1=Dv[5+2*d2]; swap_halves(x1,y1);
                Bv[0].d[d2] = pk(x0,x1); Bv[0].d[2+d2] = pk(y0,y1);
            }
            Bv[1].d[0] = pk(Dv[8],Dv[9]); Bv[1].d[1] = pk(Dv[10],Dv[11]);
            Bv[1].d[2] = ONE0; Bv[1].d[3] = Z2;

            #pragma unroll
            for (int r = 0; r < 16; ++r) Dv[r] = 0.f;
            #pragma unroll
            for (int c = 0; c < 2; ++c)
                Dv = __builtin_amdgcn_mfma_f32_32x32x16_f16(A3[c], Bv[c].v8, Dv, 0,0,0);
            #pragma unroll
            for (int r = 0; r < 12; ++r) Dv[r] = tanh_fast(Dv[r]);

            float u = 0.f;
            #pragma unroll
            for (int r = 0; r < 12; ++r) u = fmaf(w4v[r], Dv[r], u);
            u += __shfl_xor(u, 32);
            u += b4v;
            const float dd = u - uT;
            if (h == 0 && valid) { if (isB) lbd += dd * dd; else li += dd * dd; }
        }
        block_reduce_atomic(li,  sums + 1);
        block_reduce_atomic(lbd, sums + 2);
    }
}

__global__ void k_zero(double* sums) {
    if (threadIdx.x < 3) sums[threadIdx.x] = 0.0;
}

__global__ void k_fin(const double* __restrict__ sums, float* __restrict__ out,
                      int N, int NI, int NB) {
    out[0] = (float)(sums[0] / (double)N + sums[1] / (double)NI + sums[2] / (double)NB);
}

extern "C" void kernel_launch(void* const* d_in, const int* in_sizes, int n_in,
                              void* d_out, int out_size, void* d_ws, size_t ws_size,
                              hipStream_t stream) {
    const float* t_c = (const float*)d_in[0];
    const float* x_c = (const float*)d_in[1];
    const float* t_i = (const float*)d_in[2];
    const float* x_i = (const float*)d_in[3];
    const float* u_i = (const float*)d_in[4];
    const float* t_b = (const float*)d_in[5];
    const float* x_b = (const float*)d_in[6];
    const float* u_b = (const float*)d_in[7];
    const float* W1  = (const float*)d_in[8];
    const float* b1  = (const float*)d_in[9];
    const float* W2  = (const float*)d_in[10];
    const float* b2  = (const float*)d_in[11];
    const float* W3  = (const float*)d_in[12];
    const float* b3  = (const float*)d_in[13];
    const float* W4  = (const float*)d_in[14];
    const float* b4  = (const float*)d_in[15];

    const int N  = in_sizes[0];
    const int NI = in_sizes[2];
    const int NB = in_sizes[5];
    const float nu = 0.0031830988618379067f;  // 0.01/pi

    const int CBLK = 2048;
    const int DBLK = 512;

    double* sums = (double*)d_ws;

    k_zero<<<1, 64, 0, stream>>>(sums);
    k_fused<<<CBLK + DBLK, 256, 0, stream>>>(t_c, x_c, t_i, x_i, u_i, t_b, x_b, u_b,
                                             W1, b1, W2, b2, W3, b3, W4, b4,
                                             sums, N, NI, NB, CBLK, DBLK, nu);
    k_fin<<<1, 1, 0, stream>>>(sums, (float*)d_out, N, NI, NB);
}

// Round 6
// 103.007 us; speedup vs baseline: 3.5836x; 1.0927x over previous
//
#include <hip/hip_runtime.h>

#define HID 20

typedef _Float16 half8  __attribute__((ext_vector_type(8)));
typedef _Float16 half2t __attribute__((ext_vector_type(2)));
typedef float    f32x16 __attribute__((ext_vector_type(16)));

union H8 { half8 v8; half2t d[4]; };   // build fp16 fragment dword-by-dword

// tanh via exp2 + rcp: tanh(v) = 1 - 2/(exp2(v*2*log2e)+1). Saturates at +-inf.
static __device__ __forceinline__ float tanh_fast(float v) {
    const float e = __builtin_amdgcn_exp2f(v * 2.8853900817779268f);
    const float r = __builtin_amdgcn_rcpf(e + 1.0f);
    return fmaf(-2.0f, r, 1.0f);
}

// v_cvt_pkrtz_f16_f32: pack two f32 into one dword of two fp16 (RTZ).
static __device__ __forceinline__ half2t pk(float a, float b) {
    auto r = __builtin_amdgcn_cvt_pkrtz(a, b);
    half2t out;
    __builtin_memcpy(&out, &r, sizeof(out));
    return out;
}

// v_permlane32_swap_b32: new_x[l>=32] = old_y[l-32]; new_y[l<32] = old_x[l+32].
static __device__ __forceinline__ void swap_halves(float& x, float& y) {
    asm volatile("v_permlane32_swap_b32 %0, %1" : "+v"(x), "+v"(y));
}

// sum with lane^32 partner on every lane: 1 mov + 1 permlane + 1 add, no lgkm.
static __device__ __forceinline__ float xor32_sum(float u) {
    float t = u;
    swap_halves(u, t);     // u[l] = old_u[l&31]; t[l] = old_u[32|(l&31)]
    return u + t;
}

// 64-lane shuffle reduce -> cross-wave LDS -> one f64 atomic per block.
__device__ __forceinline__ void block_reduce_atomic(float local, double* dst) {
    #pragma unroll
    for (int off = 32; off > 0; off >>= 1) local += __shfl_down(local, off);
    __shared__ float parts[4];
    __syncthreads();
    const int lane = threadIdx.x & 63, wid = threadIdx.x >> 6;
    if (lane == 0) parts[wid] = local;
    __syncthreads();
    if (threadIdx.x == 0)
        atomicAdd(dst, (double)(parts[0] + parts[1] + parts[2] + parts[3]));
}

// ---------------------------------------------------------------------------
// Fused kernel. Blocks [0, CBLK): collocation (4 dual channels).
//               Blocks [CBLK, CBLK+DBLK): initial+boundary (value only).
// Swapped MFMA orientation: D = Wt * Ht, point = column = lane&31 for B and D.
//   A (Wt): M-row = lane&31 (out neuron), k = 16c + 8h + e (in neuron);
//           k==20 carries the bias; rows/cols >= 20 are zero.
//   D:      col = lane&31 (point), row = (r&3) + 8(r>>2) + 4h.
// Rows >= 20 of D are exactly 0 => epilogue only r<12; pack c=1 needs no swap.
// __launch_bounds__(256,3): cap arch VGPR+acc at ~170 -> 3 waves/SIMD.
// ---------------------------------------------------------------------------
__global__ __launch_bounds__(256, 3) void k_fused(
    const float* __restrict__ t_c, const float* __restrict__ x_c,
    const float* __restrict__ t_i, const float* __restrict__ x_i, const float* __restrict__ u_i,
    const float* __restrict__ t_b, const float* __restrict__ x_b, const float* __restrict__ u_b,
    const float* __restrict__ W1, const float* __restrict__ b1,
    const float* __restrict__ W2, const float* __restrict__ b2,
    const float* __restrict__ W3, const float* __restrict__ b3,
    const float* __restrict__ W4, const float* __restrict__ b4,
    double* __restrict__ sums,
    int N, int NI, int NB, int CBLK, int DBLK, float nu)
{
    __shared__ float4 sL[32];          // {W1_t, W1_x, b1, 0} per layer-1 slot
    const int tid = threadIdx.x;
    if (tid < 32) {
        const bool r = tid < HID;
        sL[tid] = make_float4(r ? W1[tid] : 0.f, r ? W1[HID + tid] : 0.f,
                              r ? b1[tid] : 0.f, 0.f);
    }
    __syncthreads();

    const int lane = tid & 63;
    const int h    = lane >> 5;
    const int colp = lane & 31;

    // A fragments for W2,W3 (+bias row k=20); W4 in D layout (live rows only)
    half8 A2[2], A3[2];
    #pragma unroll
    for (int c = 0; c < 2; ++c) {
        #pragma unroll
        for (int e = 0; e < 8; ++e) {
            const int i = 16 * c + 8 * h + e;
            float v2 = 0.f, v3 = 0.f;
            if (colp < HID) {
                if (i < HID)       { v2 = W2[i * HID + colp]; v3 = W3[i * HID + colp]; }
                else if (i == HID) { v2 = b2[colp];           v3 = b3[colp]; }
            }
            A2[c][e] = (_Float16)v2;
            A3[c][e] = (_Float16)v3;
        }
    }
    float w4v[12];
    #pragma unroll
    for (int r = 0; r < 12; ++r) {
        const int row = (r & 3) + 8 * (r >> 2) + 4 * h;
        w4v[r] = (row < HID) ? W4[row] : 0.0f;
    }
    const float b4v = b4[0];
    const half2t Z2   = {(_Float16)0.0f, (_Float16)0.0f};
    const half2t ONE0 = {(_Float16)1.0f, (_Float16)0.0f};
    // persistent zero accumulator: C operand of each channel's first MFMA chunk
    f32x16 FZ;
    #pragma unroll
    for (int r = 0; r < 16; ++r) FZ[r] = 0.0f;

    if ((int)blockIdx.x < CBLK) {
        // ================= collocation: 4 dual channels =================
        const int wave  = (int)blockIdx.x * 4 + (tid >> 6);
        const int nwave = CBLK * 4;
        const int ntile = (N + 31) >> 5;

        float local = 0.0f;
        int  tile  = wave;
        bool valid = false;
        float tv = 0.f, xv = 0.f;
        if (tile < ntile) {
            const int idx = (tile << 5) + colp;
            valid = idx < N;
            const int ia = valid ? idx : 0;
            tv = t_c[ia]; xv = x_c[ia];
        }
        while (tile < ntile) {
            // ---- prefetch next tile's inputs (issue before the body) ----
            const int nxt = tile + nwave;
            float ntv = 0.f, nxv = 0.f;
            bool nvalid = false;
            if (nxt < ntile) {
                const int nidx = (nxt << 5) + colp;
                nvalid = nidx < N;
                const int nia = nvalid ? nidx : 0;
                ntv = t_c[nia]; nxv = x_c[nia];
            }

            // layer-1 slot: p = t*w.x + x*w.y + w.z ; duals from (w.x, w.y)
            auto l1 = [&](int e, int c, float& vv, float& va, float& vc, float& ve) {
                const int n = 16 * c + 8 * h + e;
                const float4 w = sL[n];
                const float p  = fmaf(tv, w.x, fmaf(xv, w.y, w.z));
                const float th = tanh_fast(p);
                const float s  = fmaf(-th, th, 1.0f);
                const float q  = s * w.y;
                vv = th; va = s * w.x; vc = q; ve = -((th + th) * q) * w.y;
            };

            H8 Bv[2], Ba[2], Bc[2], Be[2];
            #pragma unroll
            for (int d2 = 0; d2 < 4; ++d2) {       // c=0, slot pairs
                float v0,a0,c0,e0, v1,a1,c1,e1;
                l1(2*d2,     0, v0,a0,c0,e0);
                l1(2*d2 + 1, 0, v1,a1,c1,e1);
                Bv[0].d[d2] = pk(v0,v1); Ba[0].d[d2] = pk(a0,a1);
                Bc[0].d[d2] = pk(c0,c1); Be[0].d[d2] = pk(e0,e1);
            }
            #pragma unroll
            for (int d2 = 0; d2 < 2; ++d2) {       // c=1, slots 16..19
                float v0,a0,c0,e0, v1,a1,c1,e1;
                l1(2*d2,     1, v0,a0,c0,e0);
                l1(2*d2 + 1, 1, v1,a1,c1,e1);
                Bv[1].d[d2] = pk(v0,v1); Ba[1].d[d2] = pk(a0,a1);
                Bc[1].d[d2] = pk(c0,c1); Be[1].d[d2] = pk(e0,e1);
            }
            Bv[1].d[2] = ONE0; Ba[1].d[2] = Z2; Bc[1].d[2] = Z2; Be[1].d[2] = Z2; // bias k=20
            Bv[1].d[3] = Z2;   Ba[1].d[3] = Z2; Bc[1].d[3] = Z2; Be[1].d[3] = Z2;

            // ---- layer 2: first chunk takes FZ as C (no per-tile zeroing) ----
            f32x16 Dv, Da, Dc, De;
            Dv = __builtin_amdgcn_mfma_f32_32x32x16_f16(A2[0], Bv[0].v8, FZ, 0,0,0);
            Da = __builtin_amdgcn_mfma_f32_32x32x16_f16(A2[0], Ba[0].v8, FZ, 0,0,0);
            Dc = __builtin_amdgcn_mfma_f32_32x32x16_f16(A2[0], Bc[0].v8, FZ, 0,0,0);
            De = __builtin_amdgcn_mfma_f32_32x32x16_f16(A2[0], Be[0].v8, FZ, 0,0,0);
            Dv = __builtin_amdgcn_mfma_f32_32x32x16_f16(A2[1], Bv[1].v8, Dv, 0,0,0);
            Da = __builtin_amdgcn_mfma_f32_32x32x16_f16(A2[1], Ba[1].v8, Da, 0,0,0);
            Dc = __builtin_amdgcn_mfma_f32_32x32x16_f16(A2[1], Bc[1].v8, Dc, 0,0,0);
            De = __builtin_amdgcn_mfma_f32_32x32x16_f16(A2[1], Be[1].v8, De, 0,0,0);

            #pragma unroll
            for (int r = 0; r < 12; ++r) {          // rows >=24 are dead
                const float zv = Dv[r], za = Da[r], zc = Dc[r], ze = De[r];
                const float th = tanh_fast(zv);
                const float s  = fmaf(-th, th, 1.0f);
                const float q  = s * zc;
                Dv[r] = th; Da[r] = s * za; Dc[r] = q;
                De[r] = fmaf(s, ze, -((th + th) * q) * zc);
            }
            // pack D -> B: c=0 via swaps; c=1 straight (h=1 side is natural 0)
            #pragma unroll
            for (int d2 = 0; d2 < 2; ++d2) {
                float x0,y0,x1,y1;
                x0=Dv[2*d2]; y0=Dv[4+2*d2]; swap_halves(x0,y0);
                x1=Dv[2*d2+1]; y1=Dv[5+2*d2]; swap_halves(x1,y1);
                Bv[0].d[d2] = pk(x0,x1); Bv[0].d[2+d2] = pk(y0,y1);
                x0=Da[2*d2]; y0=Da[4+2*d2]; swap_halves(x0,y0);
                x1=Da[2*d2+1]; y1=Da[5+2*d2]; swap_halves(x1,y1);
                Ba[0].d[d2] = pk(x0,x1); Ba[0].d[2+d2] = pk(y0,y1);
                x0=Dc[2*d2]; y0=Dc[4+2*d2]; swap_halves(x0,y0);
                x1=Dc[2*d2+1]; y1=Dc[5+2*d2]; swap_halves(x1,y1);
                Bc[0].d[d2] = pk(x0,x1); Bc[0].d[2+d2] = pk(y0,y1);
                x0=De[2*d2]; y0=De[4+2*d2]; swap_halves(x0,y0);
                x1=De[2*d2+1]; y1=De[5+2*d2]; swap_halves(x1,y1);
                Be[0].d[d2] = pk(x0,x1); Be[0].d[2+d2] = pk(y0,y1);
            }
            Bv[1].d[0] = pk(Dv[8],Dv[9]); Bv[1].d[1] = pk(Dv[10],Dv[11]);
            Ba[1].d[0] = pk(Da[8],Da[9]); Ba[1].d[1] = pk(Da[10],Da[11]);
            Bc[1].d[0] = pk(Dc[8],Dc[9]); Bc[1].d[1] = pk(Dc[10],Dc[11]);
            Be[1].d[0] = pk(De[8],De[9]); Be[1].d[1] = pk(De[10],De[11]);
            Bv[1].d[2] = ONE0; Ba[1].d[2] = Z2; Bc[1].d[2] = Z2; Be[1].d[2] = Z2;
            Bv[1].d[3] = Z2;   Ba[1].d[3] = Z2; Bc[1].d[3] = Z2; Be[1].d[3] = Z2;

            // ---- layer 3 ----
            Dv = __builtin_amdgcn_mfma_f32_32x32x16_f16(A3[0], Bv[0].v8, FZ, 0,0,0);
            Da = __builtin_amdgcn_mfma_f32_32x32x16_f16(A3[0], Ba[0].v8, FZ, 0,0,0);
            Dc = __builtin_amdgcn_mfma_f32_32x32x16_f16(A3[0], Bc[0].v8, FZ, 0,0,0);
            De = __builtin_amdgcn_mfma_f32_32x32x16_f16(A3[0], Be[0].v8, FZ, 0,0,0);
            Dv = __builtin_amdgcn_mfma_f32_32x32x16_f16(A3[1], Bv[1].v8, Dv, 0,0,0);
            Da = __builtin_amdgcn_mfma_f32_32x32x16_f16(A3[1], Ba[1].v8, Da, 0,0,0);
            Dc = __builtin_amdgcn_mfma_f32_32x32x16_f16(A3[1], Bc[1].v8, Dc, 0,0,0);
            De = __builtin_amdgcn_mfma_f32_32x32x16_f16(A3[1], Be[1].v8, De, 0,0,0);

            #pragma unroll
            for (int r = 0; r < 12; ++r) {
                const float zv = Dv[r], za = Da[r], zc = Dc[r], ze = De[r];
                const float th = tanh_fast(zv);
                const float s  = fmaf(-th, th, 1.0f);
                const float q  = s * zc;
                Dv[r] = th; Da[r] = s * za; Dc[r] = q;
                De[r] = fmaf(s, ze, -((th + th) * q) * zc);
            }

            float u = 0.f, ut = 0.f, ux = 0.f, uxx = 0.f;
            #pragma unroll
            for (int r = 0; r < 12; ++r) {
                u   = fmaf(w4v[r], Dv[r], u);
                ut  = fmaf(w4v[r], Da[r], ut);
                ux  = fmaf(w4v[r], Dc[r], ux);
                uxx = fmaf(w4v[r], De[r], uxx);
            }
            u   = xor32_sum(u) + b4v;
            ut  = xor32_sum(ut);
            ux  = xor32_sum(ux);
            uxx = xor32_sum(uxx);

            float f = fmaf(u, ux, ut);
            f = fmaf(-nu, uxx, f);
            if (h == 0 && valid) local += f * f;

            tv = ntv; xv = nxv; valid = nvalid; tile = nxt;
        }
        block_reduce_atomic(local, sums + 0);
    } else {
        // ============== initial + boundary: value channel only ==============
        const int dwave = ((int)blockIdx.x - CBLK) * 4 + (tid >> 6);
        const int dnw   = DBLK * 4;
        const int nti   = (NI + 31) >> 5;
        const int ntb   = (NB + 31) >> 5;

        float li = 0.0f, lbd = 0.0f;
        for (int t2 = dwave; t2 < nti + ntb; t2 += dnw) {
            const bool isB = t2 >= nti;               // wave-uniform
            const float* tp = isB ? t_b : t_i;
            const float* xp = isB ? x_b : x_i;
            const float* up = isB ? u_b : u_i;
            const int    n_ = isB ? NB  : NI;
            const int  idx  = (((isB ? t2 - nti : t2) << 5)) + colp;
            const bool valid = idx < n_;
            const int  ia    = valid ? idx : 0;
            const float tv = tp[ia], xv = xp[ia], uT = up[ia];

            auto l1v = [&](int e, int c) -> float {
                const int n = 16 * c + 8 * h + e;
                const float4 w = sL[n];
                return tanh_fast(fmaf(tv, w.x, fmaf(xv, w.y, w.z)));
            };

            H8 Bv[2];
            #pragma unroll
            for (int d2 = 0; d2 < 4; ++d2)
                Bv[0].d[d2] = pk(l1v(2*d2, 0), l1v(2*d2+1, 0));
            #pragma unroll
            for (int d2 = 0; d2 < 2; ++d2)
                Bv[1].d[d2] = pk(l1v(2*d2, 1), l1v(2*d2+1, 1));
            Bv[1].d[2] = ONE0; Bv[1].d[3] = Z2;

            f32x16 Dv;
            Dv = __builtin_amdgcn_mfma_f32_32x32x16_f16(A2[0], Bv[0].v8, FZ, 0,0,0);
            Dv = __builtin_amdgcn_mfma_f32_32x32x16_f16(A2[1], Bv[1].v8, Dv, 0,0,0);
            #pragma unroll
            for (int r = 0; r < 12; ++r) Dv[r] = tanh_fast(Dv[r]);

            #pragma unroll
            for (int d2 = 0; d2 < 2; ++d2) {
                float x0,y0,x1,y1;
                x0=Dv[2*d2]; y0=Dv[4+2*d2]; swap_halves(x0,y0);
                x1=Dv[2*d2+1]; y1=Dv[5+2*d2]; swap_halves(x1,y1);
                Bv[0].d[d2] = pk(x0,x1); Bv[0].d[2+d2] = pk(y0,y1);
            }
            Bv[1].d[0] = pk(Dv[8],Dv[9]); Bv[1].d[1] = pk(Dv[10],Dv[11]);
            Bv[1].d[2] = ONE0; Bv[1].d[3] = Z2;

            Dv = __builtin_amdgcn_mfma_f32_32x32x16_f16(A3[0], Bv[0].v8, FZ, 0,0,0);
            Dv = __builtin_amdgcn_mfma_f32_32x32x16_f16(A3[1], Bv[1].v8, Dv, 0,0,0);
            #pragma unroll
            for (int r = 0; r < 12; ++r) Dv[r] = tanh_fast(Dv[r]);

            float u = 0.f;
            #pragma unroll
            for (int r = 0; r < 12; ++r) u = fmaf(w4v[r], Dv[r], u);
            u = xor32_sum(u) + b4v;
            const float dd = u - uT;
            if (h == 0 && valid) { if (isB) lbd += dd * dd; else li += dd * dd; }
        }
        block_reduce_atomic(li,  sums + 1);
        block_reduce_atomic(lbd, sums + 2);
    }
}

__global__ void k_zero(double* sums) {
    if (threadIdx.x < 3) sums[threadIdx.x] = 0.0;
}

__global__ void k_fin(const double* __restrict__ sums, float* __restrict__ out,
                      int N, int NI, int NB) {
    out[0] = (float)(sums[0] / (double)N + sums[1] / (double)NI + sums[2] / (double)NB);
}

extern "C" void kernel_launch(void* const* d_in, const int* in_sizes, int n_in,
                              void* d_out, int out_size, void* d_ws, size_t ws_size,
                              hipStream_t stream) {
    const float* t_c = (const float*)d_in[0];
    const float* x_c = (const float*)d_in[1];
    const float* t_i = (const float*)d_in[2];
    const float* x_i = (const float*)d_in[3];
    const float* u_i = (const float*)d_in[4];
    const float* t_b = (const float*)d_in[5];
    const float* x_b = (const float*)d_in[6];
    const float* u_b = (const float*)d_in[7];
    const float* W1  = (const float*)d_in[8];
    const float* b1  = (const float*)d_in[9];
    const float* W2  = (const float*)d_in[10];
    const float* b2  = (const float*)d_in[11];
    const float* W3  = (const float*)d_in[12];
    const float* b3  = (const float*)d_in[13];
    const float* W4  = (const float*)d_in[14];
    const float* b4  = (const float*)d_in[15];

    const int N  = in_sizes[0];
    const int NI = in_sizes[2];
    const int NB = in_sizes[5];
    const float nu = 0.0031830988618379067f;  // 0.01/pi

    const int CBLK = 2048;
    const int DBLK = 512;

    double* sums = (double*)d_ws;

    k_zero<<<1, 64, 0, stream>>>(sums);
    k_fused<<<CBLK + DBLK, 256, 0, stream>>>(t_c, x_c, t_i, x_i, u_i, t_b, x_b, u_b,
                                             W1, b1, W2, b2, W3, b3, W4, b4,
                                             sums, N, NI, NB, CBLK, DBLK, nu);
    k_fin<<<1, 1, 0, stream>>>(sums, (float*)d_out, N, NI, NB);
}